// Round 1
// 606.963 us; speedup vs baseline: 1.0645x; 1.0645x over previous
//
#include <hip/hip_runtime.h>
#include <hip/hip_bf16.h>
#include <math.h>

// Problem constants: N=64, L=1024, H=1024
#define N_  64
#define L_  1024
#define H_  1024
#define NL_ (N_ * L_)
#define NT_ 16   // K tiles of 64 in the score GEMM

typedef __attribute__((ext_vector_type(8))) short bf16x8;   // 8 bf16 = 4 VGPRs
typedef __attribute__((ext_vector_type(4))) float f32x4;
typedef unsigned short ushort_t;
typedef unsigned int uint_t;

// ---------------------------------------------------------------------------
// K0: fp32 -> bf16 (RNE), grid-strided, 8 elements/thread/iter, 16B stores
// ---------------------------------------------------------------------------
__device__ inline ushort_t f32_to_bf16_rne(float f) {
    uint_t u = __float_as_uint(f);
    u += 0x7FFFu + ((u >> 16) & 1u);
    return (ushort_t)(u >> 16);
}

__global__ __launch_bounds__(256) void convert_bf16_kernel(const float* __restrict__ src,
                                                           ushort_t* __restrict__ dst,
                                                           size_t nvec8) {
    size_t stride = (size_t)gridDim.x * 256;
    for (size_t g = (size_t)blockIdx.x * 256 + threadIdx.x; g < nvec8; g += stride) {
        size_t i = g * 8;
        float4 a = *(const float4*)(src + i);
        float4 b = *(const float4*)(src + i + 4);
        union { bf16x8 v; ushort_t u[8]; } o;
        o.u[0] = f32_to_bf16_rne(a.x); o.u[1] = f32_to_bf16_rne(a.y);
        o.u[2] = f32_to_bf16_rne(a.z); o.u[3] = f32_to_bf16_rne(a.w);
        o.u[4] = f32_to_bf16_rne(b.x); o.u[5] = f32_to_bf16_rne(b.y);
        o.u[6] = f32_to_bf16_rne(b.z); o.u[7] = f32_to_bf16_rne(b.w);
        *(bf16x8*)(dst + i) = o.v;
    }
}

// ---------------------------------------------------------------------------
// K1: dh[n][k] = sum_h ddec[n][h] * Wh[k][h]   (fp32, tiny: 0.13 GFLOP)
// ---------------------------------------------------------------------------
__global__ __launch_bounds__(256) void dh_kernel(const float* __restrict__ ddec,
                                                 const float* __restrict__ Wh,
                                                 float* __restrict__ dh) {
    int i = blockIdx.x * 256 + threadIdx.x;
    int n = i >> 10;
    const float* a = ddec + (size_t)n * H_;
    const float* w = Wh + (size_t)(i & (H_ - 1)) * H_;
    float acc = 0.f;
#pragma unroll 8
    for (int h = 0; h < H_; h += 4) {
        float4 av = *(const float4*)(a + h);
        float4 wv = *(const float4*)(w + h);
        acc += av.x * wv.x + av.y * wv.y + av.z * wv.z + av.w * wv.w;
    }
    dh[i] = acc;
}

// ---------------------------------------------------------------------------
// K2: MFMA score GEMM — 256x256 tile, BK=64, 8 waves (2Mx4N), 8-phase-style
// schedule with counted vmcnt (never 0 in the main loop) + setprio.
//   C[i][k] = sum_h enc_bf[i][h] * ws_bf[k][h]
//   score[i] += sum_k v[k] * tanh(dh[n][k] + C[i][k])
//
// LDS 128KB: A[2][256][64] | B[2][256][64] bf16, chunk-XOR swizzle (c ^= r&7)
// applied via pre-swizzled GLOBAL source (global_load_lds dest must be linear).
//
// Staging ownership == readership (this is what makes per-wave counted vmcnt a
// valid cross-wave guarantee):
//   A half  (128 rows): staged by the 4 waves of that M-group, read by same.
//   B 64-row group:     staged by its wc-pair {w, w+4}, read by same.
// Per-wave issue stream per tile t (staging tile t+1):
//   p1: A x2, p2: A x2, p3: B-slice1 x2, p4: B-slice2 x2
// Consumption at tile t+1: p1 needs {A all, slice1}, p2 needs {slice2}.
// => exactly two waits per tile, both vmcnt(2): end-p1 and end-p4.
// Last tile stages a wrapped (kt+1)&15 tile: addresses valid, data unused,
// so wait counts stay uniform (no vmcnt(0) in the loop).
//
// Grid 1024 1-D: k_tile=(b>>3)&3, i_tile=(b&7)|((b>>5)<<3) -> the 4 k-tiles of
// an i-tile share an XCD (b%8) and are dispatched within a 32-id span.
// ---------------------------------------------------------------------------
__device__ __forceinline__ void glds(const ushort_t* g, ushort_t* l) {
    __builtin_amdgcn_global_load_lds((const __attribute__((address_space(1))) void*)g,
                                     (__attribute__((address_space(3))) void*)l,
                                     16, 0, 0);
}

__global__ __launch_bounds__(512, 2) void score_mfma_kernel(const ushort_t* __restrict__ enc_bf,
                                                            const ushort_t* __restrict__ ws_bf,
                                                            const float* __restrict__ dh,
                                                            const float* __restrict__ v,
                                                            float* __restrict__ score) {
    __shared__ ushort_t lds[65536];   // [A0|A1|B0|B1] x 16384 shorts = 128 KB

    const int b  = blockIdx.x;
    const int i0 = ((b & 7) | ((b >> 5) << 3)) << 8;   // i-tile base (256 rows)
    const int k0 = ((b >> 3) & 3) << 8;                // k-tile base (256 cols)
    const int tid  = threadIdx.x;
    const int lane = tid & 63;
    const int w    = tid >> 6;          // wave 0..7
    const int wr   = (w >> 2) << 7;     // wave row base: 0 / 128
    const int wc   = (w & 3) << 6;      // wave col base: 0/64/128/192
    const int m    = lane & 15;
    const int q    = lane >> 4;
    const int half = w >> 2;            // A-half owner / B sub-index
    const int grp  = w & 3;             // B group owner / A sub-index

    // staging: per-lane source offset (8 rows x 8 chunks, chunk = c ^ (row&7))
    const int g_lane = (lane >> 3) * H_ + (((lane & 7) ^ (lane >> 3)) << 3);
    // LDS read chunk offsets (shorts) for k-step 0/1; rows read have r&7 == m&7
    const int csw0 = ((q ^ (m & 7)) << 3);
    const int csw1 = (((4 | q) ^ (m & 7)) << 3);

    const int rA0 = (half << 7) + (grp << 5);   // this wave's 4 A-stage rows base
    const int rB0 = (grp << 6) + (half << 4);   // this wave's B-stage rows base

    // ---- prologue: stage tile 0 fully, one-time drain ----
    {
        const ushort_t* gA = enc_bf + (size_t)i0 * H_ + g_lane;
        const ushort_t* gB = ws_bf  + (size_t)k0 * H_ + g_lane;
        ushort_t* An = lds;            // buf 0
        ushort_t* Bn = lds + 32768;
        glds(gA + (size_t)(rA0 +  0) * H_, An + (rA0 +  0) * 64);
        glds(gA + (size_t)(rA0 +  8) * H_, An + (rA0 +  8) * 64);
        glds(gA + (size_t)(rA0 + 16) * H_, An + (rA0 + 16) * 64);
        glds(gA + (size_t)(rA0 + 24) * H_, An + (rA0 + 24) * 64);
        glds(gB + (size_t)(rB0 +  0) * H_, Bn + (rB0 +  0) * 64);
        glds(gB + (size_t)(rB0 +  8) * H_, Bn + (rB0 +  8) * 64);
        glds(gB + (size_t)(rB0 + 32) * H_, Bn + (rB0 + 32) * 64);
        glds(gB + (size_t)(rB0 + 40) * H_, Bn + (rB0 + 40) * 64);
        asm volatile("s_waitcnt vmcnt(0)" ::: "memory");
        __builtin_amdgcn_s_barrier();
    }

    f32x4 acc[8][4];
#pragma unroll
    for (int a = 0; a < 8; a++)
#pragma unroll
        for (int c = 0; c < 4; c++)
            acc[a][c] = (f32x4){0.f, 0.f, 0.f, 0.f};

    const int rowA = wr + m;
    const int rowB = wc + m;

#pragma unroll 2
    for (int kt = 0; kt < NT_; ++kt) {
        ushort_t* Ac = lds + ((kt & 1) << 14);
        ushort_t* Bc = lds + 32768 + ((kt & 1) << 14);
        ushort_t* An = lds + (((kt + 1) & 1) << 14);
        ushort_t* Bn = lds + 32768 + (((kt + 1) & 1) << 14);
        const int h0n = ((kt + 1) & (NT_ - 1)) << 6;   // next tile K offset (wraps)
        const ushort_t* gA = enc_bf + (size_t)i0 * H_ + h0n + g_lane;
        const ushort_t* gB = ws_bf  + (size_t)k0 * H_ + h0n + g_lane;

        bf16x8 af[8], b0, b1, b2, b3;

        // ---------- phase 1: cols 0,1 x k-step 0 ----------
#pragma unroll
        for (int ti = 0; ti < 8; ti++)
            af[ti] = *(const bf16x8*)(Ac + (rowA + ti * 16) * 64 + csw0);
        b0 = *(const bf16x8*)(Bc + (rowB +  0) * 64 + csw0);
        b1 = *(const bf16x8*)(Bc + (rowB + 16) * 64 + csw0);
        glds(gA + (size_t)(rA0 + 0) * H_, An + (rA0 + 0) * 64);
        glds(gA + (size_t)(rA0 + 8) * H_, An + (rA0 + 8) * 64);
        __builtin_amdgcn_s_barrier();
        asm volatile("s_waitcnt lgkmcnt(0)" ::: "memory");
        __builtin_amdgcn_sched_barrier(0);
        __builtin_amdgcn_s_setprio(1);
#pragma unroll
        for (int ti = 0; ti < 8; ti++)
            acc[ti][0] = __builtin_amdgcn_mfma_f32_16x16x32_bf16(af[ti], b0, acc[ti][0], 0, 0, 0);
#pragma unroll
        for (int ti = 0; ti < 8; ti++)
            acc[ti][1] = __builtin_amdgcn_mfma_f32_16x16x32_bf16(af[ti], b1, acc[ti][1], 0, 0, 0);
        __builtin_amdgcn_s_setprio(0);
        asm volatile("s_waitcnt vmcnt(2)" ::: "memory");   // completes prev slice2
        __builtin_amdgcn_s_barrier();

        // ---------- phase 2: cols 2,3 x k-step 0 ----------
        b2 = *(const bf16x8*)(Bc + (rowB + 32) * 64 + csw0);
        b3 = *(const bf16x8*)(Bc + (rowB + 48) * 64 + csw0);
        glds(gA + (size_t)(rA0 + 16) * H_, An + (rA0 + 16) * 64);
        glds(gA + (size_t)(rA0 + 24) * H_, An + (rA0 + 24) * 64);
        __builtin_amdgcn_s_barrier();
        asm volatile("s_waitcnt lgkmcnt(0)" ::: "memory");
        __builtin_amdgcn_sched_barrier(0);
        __builtin_amdgcn_s_setprio(1);
#pragma unroll
        for (int ti = 0; ti < 8; ti++)
            acc[ti][2] = __builtin_amdgcn_mfma_f32_16x16x32_bf16(af[ti], b2, acc[ti][2], 0, 0, 0);
#pragma unroll
        for (int ti = 0; ti < 8; ti++)
            acc[ti][3] = __builtin_amdgcn_mfma_f32_16x16x32_bf16(af[ti], b3, acc[ti][3], 0, 0, 0);
        __builtin_amdgcn_s_setprio(0);
        __builtin_amdgcn_s_barrier();

        // ---------- phase 3: cols 0,1 x k-step 1 ----------
#pragma unroll
        for (int ti = 0; ti < 8; ti++)
            af[ti] = *(const bf16x8*)(Ac + (rowA + ti * 16) * 64 + csw1);
        b0 = *(const bf16x8*)(Bc + (rowB +  0) * 64 + csw1);
        b1 = *(const bf16x8*)(Bc + (rowB + 16) * 64 + csw1);
        glds(gB + (size_t)(rB0 + 0) * H_, Bn + (rB0 + 0) * 64);
        glds(gB + (size_t)(rB0 + 8) * H_, Bn + (rB0 + 8) * 64);
        __builtin_amdgcn_s_barrier();
        asm volatile("s_waitcnt lgkmcnt(0)" ::: "memory");
        __builtin_amdgcn_sched_barrier(0);
        __builtin_amdgcn_s_setprio(1);
#pragma unroll
        for (int ti = 0; ti < 8; ti++)
            acc[ti][0] = __builtin_amdgcn_mfma_f32_16x16x32_bf16(af[ti], b0, acc[ti][0], 0, 0, 0);
#pragma unroll
        for (int ti = 0; ti < 8; ti++)
            acc[ti][1] = __builtin_amdgcn_mfma_f32_16x16x32_bf16(af[ti], b1, acc[ti][1], 0, 0, 0);
        __builtin_amdgcn_s_setprio(0);
        __builtin_amdgcn_s_barrier();

        // ---------- phase 4: cols 2,3 x k-step 1 ----------
        b2 = *(const bf16x8*)(Bc + (rowB + 32) * 64 + csw1);
        b3 = *(const bf16x8*)(Bc + (rowB + 48) * 64 + csw1);
        glds(gB + (size_t)(rB0 + 32) * H_, Bn + (rB0 + 32) * 64);
        glds(gB + (size_t)(rB0 + 40) * H_, Bn + (rB0 + 40) * 64);
        __builtin_amdgcn_s_barrier();
        asm volatile("s_waitcnt lgkmcnt(0)" ::: "memory");
        __builtin_amdgcn_sched_barrier(0);
        __builtin_amdgcn_s_setprio(1);
#pragma unroll
        for (int ti = 0; ti < 8; ti++)
            acc[ti][2] = __builtin_amdgcn_mfma_f32_16x16x32_bf16(af[ti], b2, acc[ti][2], 0, 0, 0);
#pragma unroll
        for (int ti = 0; ti < 8; ti++)
            acc[ti][3] = __builtin_amdgcn_mfma_f32_16x16x32_bf16(af[ti], b3, acc[ti][3], 0, 0, 0);
        __builtin_amdgcn_s_setprio(0);
        asm volatile("s_waitcnt vmcnt(2)" ::: "memory");   // completes next A + slice1
        __builtin_amdgcn_s_barrier();
    }

    // Epilogue: x = dh + C; s_row += v[k] * tanh(x); 16-lane shfl reduce over k,
    // one atomicAdd per (row, wave) into d_ws score buffer.
    const int nb = i0 >> 10;            // batch index (tile never crosses n)
    float vv[4], dhv[4];
#pragma unroll
    for (int tj = 0; tj < 4; tj++) {
        int k = k0 + wc + tj * 16 + m;  // C/D col = lane&15
        vv[tj]  = v[k];
        dhv[tj] = dh[nb * H_ + k];
    }
#pragma unroll
    for (int ti = 0; ti < 8; ti++) {
#pragma unroll
        for (int reg = 0; reg < 4; reg++) {
            float s = 0.f;
#pragma unroll
            for (int tj = 0; tj < 4; tj++) {
                float x  = dhv[tj] + acc[ti][tj][reg];
                float e2 = __expf(2.f * x);
                s += vv[tj] * (1.f - 2.f / (e2 + 1.f));   // tanh, saturates +/-1
            }
            s += __shfl_xor(s, 1);
            s += __shfl_xor(s, 2);
            s += __shfl_xor(s, 4);
            s += __shfl_xor(s, 8);
            if (m == 0) {
                int i_local = wr + ti * 16 + q * 4 + reg;   // C/D row = quad*4+reg
                atomicAdd(&score[i0 + i_local], s);
            }
        }
    }
}

// ---------------------------------------------------------------------------
// K3: masked softmax over L per batch row; plain stores to d_out[65536..]
// ---------------------------------------------------------------------------
__global__ __launch_bounds__(256) void softmax_kernel(const float* __restrict__ score,
                                                      const int* __restrict__ mask,
                                                      float* __restrict__ attn) {
    const int n = blockIdx.x;
    const int t = threadIdx.x;
    __shared__ float redmax[4];
    __shared__ float redsum[4];

    float s[4];
    int   mk[4];
    float mymax = -INFINITY;
#pragma unroll
    for (int j = 0; j < 4; j++) {
        int l = t + j * 256;
        mk[j] = mask[n * L_ + l];
        s[j] = mk[j] ? -INFINITY : score[n * L_ + l];
        mymax = fmaxf(mymax, s[j]);
    }
#pragma unroll
    for (int off = 1; off < 64; off <<= 1)
        mymax = fmaxf(mymax, __shfl_xor(mymax, off));
    if ((t & 63) == 0) redmax[t >> 6] = mymax;
    __syncthreads();
    float gmax = fmaxf(fmaxf(redmax[0], redmax[1]), fmaxf(redmax[2], redmax[3]));

    float e[4];
    float mysum = 0.f;
#pragma unroll
    for (int j = 0; j < 4; j++) {
        e[j] = mk[j] ? 0.f : __expf(s[j] - gmax);
        mysum += e[j];
    }
#pragma unroll
    for (int off = 1; off < 64; off <<= 1)
        mysum += __shfl_xor(mysum, off);
    if ((t & 63) == 0) redsum[t >> 6] = mysum;
    __syncthreads();
    float gsum = redsum[0] + redsum[1] + redsum[2] + redsum[3];
    float inv = 1.f / gsum;
#pragma unroll
    for (int j = 0; j < 4; j++)
        attn[n * L_ + t + j * 256] = e[j] * inv;
}

// ---------------------------------------------------------------------------
// K4a: context partials — NO atomics to d_out.
// grid (64, 8): block (n, L-chunk of 128); 128 threads, 8 h each (bf16x8,
// 16B/lane). Partial sums -> d_ws cpart[lc][n][h] with plain float4 stores.
// ---------------------------------------------------------------------------
__global__ __launch_bounds__(128) void context_partial_kernel(const ushort_t* __restrict__ enc_bf,
                                                              const float* __restrict__ attn,
                                                              float* __restrict__ cpart) {
    const int n  = blockIdx.x;
    const int lc = blockIdx.y;
    const int l0 = lc * 128;
    const int t  = threadIdx.x;      // 0..127
    const int h0 = t * 8;

    __shared__ float w[128];
    w[t] = attn[n * L_ + l0 + t];
    __syncthreads();

    const ushort_t* base = enc_bf + (size_t)n * L_ * H_ + (size_t)l0 * H_ + h0;
    float acc[8] = {};
#pragma unroll 4
    for (int l = 0; l < 128; l++) {
        union { bf16x8 v; ushort_t u[8]; } e;
        e.v = *(const bf16x8*)(base + (size_t)l * H_);
        float wl = w[l];
#pragma unroll
        for (int j = 0; j < 8; j++)
            acc[j] += wl * __uint_as_float(((uint_t)e.u[j]) << 16);
    }
    float* dst = cpart + ((size_t)lc * N_ + n) * H_ + h0;
    *(float4*)(dst + 0) = (float4){acc[0], acc[1], acc[2], acc[3]};
    *(float4*)(dst + 4) = (float4){acc[4], acc[5], acc[6], acc[7]};
}

// ---------------------------------------------------------------------------
// K4b: reduce 8 partials -> ctx, plain stores to d_out
// ---------------------------------------------------------------------------
__global__ __launch_bounds__(256) void context_reduce_kernel(const float* __restrict__ cpart,
                                                             float* __restrict__ ctx) {
    int i = blockIdx.x * 256 + threadIdx.x;   // 0..65535  (= n*H + h)
    float s = 0.f;
#pragma unroll
    for (int lc = 0; lc < 8; lc++)
        s += cpart[(size_t)lc * N_ * H_ + i];
    ctx[i] = s;
}

// ---------------------------------------------------------------------------
extern "C" void kernel_launch(void* const* d_in, const int* in_sizes, int n_in,
                              void* d_out, int out_size, void* d_ws, size_t ws_size,
                              hipStream_t stream) {
    const float* ddec = (const float*)d_in[0];   // [64,1024] f32
    const float* enc  = (const float*)d_in[1];   // [64,1024,1024] f32
    const int*   mask = (const int*)d_in[2];     // [64,1024]
    const float* Wh   = (const float*)d_in[3];   // [1024,1024] f32
    const float* Ws   = (const float*)d_in[4];   // [1024,1024] f32
    const float* v    = (const float*)d_in[5];   // [1024] f32

    float* out_ctx  = (float*)d_out;             // [64,1024]
    float* out_attn = out_ctx + N_ * H_;         // [64,1024]

    // ws: enc_bf 128MB | ws_bf 2MB | dh 256KB | score 256KB | cpart 2MB
    ushort_t* enc_bf = (ushort_t*)d_ws;
    ushort_t* ws_bf  = enc_bf + (size_t)NL_ * H_;
    float*    dh     = (float*)(ws_bf + (size_t)H_ * H_);
    float*    score  = dh + N_ * H_;
    float*    cpart  = score + NL_;

    convert_bf16_kernel<<<4096, 256, 0, stream>>>(enc, enc_bf, (size_t)NL_ * H_ / 8);
    convert_bf16_kernel<<<512, 256, 0, stream>>>(Ws, ws_bf, (size_t)H_ * H_ / 8);

    hipMemsetAsync(score, 0, (size_t)NL_ * sizeof(float), stream);

    dh_kernel<<<NL_ / 256, 256, 0, stream>>>(ddec, Wh, dh);

    score_mfma_kernel<<<1024, 512, 0, stream>>>(enc_bf, ws_bf, dh, v, score);

    softmax_kernel<<<N_, 256, 0, stream>>>(score, mask, out_attn);

    dim3 g4(N_, 8);
    context_partial_kernel<<<g4, 128, 0, stream>>>(enc_bf, out_attn, cpart);
    context_reduce_kernel<<<NL_ / 1024 * 4, 256, 0, stream>>>(cpart, out_ctx);
}